// Round 1
// baseline (127.319 us; speedup 1.0000x reference)
//
#include <hip/hip_runtime.h>
#include <math.h>

// ---------------------------------------------------------------------------
// PhysicsResonatorBank: B=8 notes, K=80 partials, NB=16 noise bands,
// N = n_frames*256 samples. out[b][c][n], c in {L,R}.
//
// Accuracy strategy: replicate the reference's f32 rounding chain for the
// oscillator phase (ph = fl(fl(2pi*f) * t), t = fl(n * fl(1/44100))), then
// evaluate sin(ph) with an exact f64 range reduction of that f32 phase.
// Everything else (env exp, beat cos, softmax, pan) has negligible
// sensitivity -> fast native intrinsics.
// ---------------------------------------------------------------------------

#define KMAX 128
#define NBMAX 32

// workspace layout (floats):
//  pf  [B*K]  : fl(2pi * freq)
//  cL  [B*K]  : amp * gainL   (0 for dead partials)
//  cR  [B*K]  : amp * gainR
//  it1 [K], it2 [K], a1s [K], oma1 [K], wb [K], hd [K]
//  bg  [NB], wn [NB]
//  nl  [B], itn [1]

__device__ __forceinline__ float sin_acc(float ph) {
    // exact reduction of the f32 phase in f64, then hw sine on small arg
    double d = (double)ph;
    double q = rint(d * 1.5915494309189535e-01);   // / (2*pi)
    double r = fma(q, -6.283185307179586, d);      // |r| <= pi, err ~1e-12
    return __sinf((float)r);
}

__global__ void pr_precomp(const float* __restrict__ f0,
                           const float* __restrict__ vel,
                           const float* __restrict__ pslope,
                           const float* __restrict__ pinter,
                           const float* __restrict__ log_tau1,
                           const float* __restrict__ log_tau2,
                           const float* __restrict__ logit_a1,
                           const float* __restrict__ log_beat_hz,
                           const float* __restrict__ logit_beat_depth,
                           const float* __restrict__ log_A0,
                           const float* __restrict__ harm_detune,
                           const float* __restrict__ noise_band_gain,
                           const float* __restrict__ plog_tau_noise,
                           const float* __restrict__ plog_noise_level,
                           const float* __restrict__ ppan_scale,
                           float* __restrict__ ws, int B, int K, int NB) {
    const int tid = threadIdx.x;
    const float two_pi = (float)(2.0 * 3.14159265358979323846);
    const float slope = pslope[0], inter = pinter[0], pan_scale = ppan_scale[0];

    float* pf  = ws;
    float* cL  = ws + (size_t)B * K;
    float* cR  = ws + (size_t)2 * B * K;
    float* it1 = ws + (size_t)3 * B * K;
    float* it2 = it1 + K;
    float* a1s = it2 + K;
    float* om1 = a1s + K;
    float* wb  = om1 + K;
    float* hd  = wb + K;
    float* bg  = hd + K;
    float* wn  = bg + NB;
    float* nl  = wn + NB;
    float* itn = nl + B;

    for (int i = tid; i < B * K; i += blockDim.x) {
        int b = i / K, k = i % K;
        float f0b = f0[b];
        float kf = (float)(k + 1);
        float midi = 69.0f + 12.0f * log2f(f0b / 440.0f);
        float mn = (midi - 21.0f) / 87.0f;
        float z = slope * mn + inter;
        z = fminf(fmaxf(z, -14.0f), -4.0f);
        float Binh = expf(z);
        float freq = (f0b * kf) * sqrtf(1.0f + Binh * (kf * kf));
        freq = freq * (1.0f + harm_detune[k]);
        float alive = (freq < 22050.0f) ? 1.0f : 0.0f;
        float amp = expf(log_A0[k]) * vel[b] * alive;
        int km1 = (K - 1) > 1 ? (K - 1) : 1;
        float pini = ((float)k / (float)km1 * 2.0f - 1.0f) * 0.1f;
        float pan = tanhf(pini * expf(pan_scale));
        float gl = sqrtf(0.5f * (1.0f - pan));
        float gr = sqrtf(0.5f * (1.0f + pan));
        pf[i] = two_pi * freq;
        cL[i] = amp * gl;
        cR[i] = amp * gr;
    }
    for (int k = tid; k < K; k += blockDim.x) {
        it1[k] = 1.0f / expf(log_tau1[k]);
        it2[k] = 1.0f / expf(log_tau2[k]);
        float a1 = 1.0f / (1.0f + expf(-logit_a1[k]));
        a1s[k] = a1;
        om1[k] = 1.0f - a1;
        wb[k] = two_pi * expf(log_beat_hz[k]);
        hd[k] = 0.5f * (1.0f / (1.0f + expf(-logit_beat_depth[k])));
    }
    for (int j = tid; j < NB; j += blockDim.x) {
        float m = -1e30f;
        for (int q = 0; q < NB; ++q) m = fmaxf(m, noise_band_gain[q]);
        float ssum = 0.0f;
        for (int q = 0; q < NB; ++q) ssum += expf(noise_band_gain[q] - m);
        float start = logf(200.0f), stop = logf(20000.0f);
        float step = (stop - start) / (float)(NB - 1);
        float lin = (j == NB - 1) ? stop : (start + (float)j * step);
        float nf = expf(lin);
        float na = (nf < 22050.0f) ? 1.0f : 0.0f;
        bg[j] = (expf(noise_band_gain[j] - m) / ssum) * na;
        wn[j] = two_pi * nf;
    }
    for (int b = tid; b < B; b += blockDim.x)
        nl[b] = expf(plog_noise_level[0]) * vel[b];
    if (tid == 0) itn[0] = 1.0f / expf(plog_tau_noise[0]);
}

__global__ __launch_bounds__(256) void pr_synth(const float* __restrict__ ws,
                                                float* __restrict__ out,
                                                int B, int K, int NB, int N) {
    const float* pf  = ws;
    const float* cL  = ws + (size_t)B * K;
    const float* cR  = ws + (size_t)2 * B * K;
    const float* it1 = ws + (size_t)3 * B * K;
    const float* it2 = it1 + K;
    const float* a1s = it2 + K;
    const float* om1 = a1s + K;
    const float* wb  = om1 + K;
    const float* hd  = wb + K;
    const float* bg  = hd + K;
    const float* wn  = bg + NB;
    const float* nl  = wn + NB;
    const float* itn = nl + B;

    const int b = blockIdx.y;
    const int n = blockIdx.x * blockDim.x + threadIdx.x;

    __shared__ float s_pf[KMAX], s_cL[KMAX], s_cR[KMAX];
    __shared__ float s_it1[KMAX], s_it2[KMAX], s_a1[KMAX], s_om[KMAX];
    __shared__ float s_wb[KMAX], s_hd[KMAX];
    __shared__ float s_bg[NBMAX], s_wn[NBMAX];

    for (int i = threadIdx.x; i < K; i += blockDim.x) {
        s_pf[i]  = pf[(size_t)b * K + i];
        s_cL[i]  = cL[(size_t)b * K + i];
        s_cR[i]  = cR[(size_t)b * K + i];
        s_it1[i] = it1[i];
        s_it2[i] = it2[i];
        s_a1[i]  = a1s[i];
        s_om[i]  = om1[i];
        s_wb[i]  = wb[i];
        s_hd[i]  = hd[i];
    }
    for (int i = threadIdx.x; i < NB; i += blockDim.x) {
        s_bg[i] = bg[i];
        s_wn[i] = wn[i];
    }
    __syncthreads();
    if (n >= N) return;

    const float t = (float)n * (float)(1.0 / 44100.0);

    float accL = 0.0f, accR = 0.0f;
    for (int k = 0; k < K; ++k) {
        float cl = s_cL[k], cr = s_cR[k];
        if (cl == 0.0f && cr == 0.0f) continue;  // dead partial (uniform in block)
        float e1 = __expf(-t * s_it1[k]);
        float e2 = __expf(-t * s_it2[k]);
        float env = s_a1[k] * e1 + s_om[k] * e2;
        float beat = fmaf(s_hd[k], __cosf(s_wb[k] * t) - 1.0f, 1.0f);
        float eb = env * beat;
        float sv = sin_acc(s_pf[k] * t);
        float p = eb * sv;
        accL = fmaf(cl, p, accL);
        accR = fmaf(cr, p, accR);
    }

    float ns = 0.0f;
    for (int j = 0; j < NB; ++j)
        ns = fmaf(s_bg[j], sin_acc(s_wn[j] * t), ns);
    float nenv = __expf(-t * itn[0]);
    float nois = nl[b] * (ns * nenv);

    out[((size_t)b * 2 + 0) * N + n] = accL + nois;
    out[((size_t)b * 2 + 1) * N + n] = accR + nois;
}

extern "C" void kernel_launch(void* const* d_in, const int* in_sizes, int n_in,
                              void* d_out, int out_size, void* d_ws, size_t ws_size,
                              hipStream_t stream) {
    const float* f0    = (const float*)d_in[0];
    const float* vel   = (const float*)d_in[1];
    const float* slope = (const float*)d_in[2];
    const float* inter = (const float*)d_in[3];
    const float* lt1   = (const float*)d_in[4];
    const float* lt2   = (const float*)d_in[5];
    const float* la1   = (const float*)d_in[6];
    const float* lbh   = (const float*)d_in[7];
    const float* lbd   = (const float*)d_in[8];
    const float* lA0   = (const float*)d_in[9];
    const float* hdet  = (const float*)d_in[10];
    const float* nbg   = (const float*)d_in[11];
    const float* ltn   = (const float*)d_in[12];
    const float* lnl   = (const float*)d_in[13];
    const float* pans  = (const float*)d_in[14];

    const int B  = in_sizes[0];
    const int K  = in_sizes[4];
    const int NB = in_sizes[11];
    const int N  = out_size / (2 * B);

    float* ws = (float*)d_ws;

    hipLaunchKernelGGL(pr_precomp, dim3(1), dim3(256), 0, stream,
                       f0, vel, slope, inter, lt1, lt2, la1, lbh, lbd, lA0,
                       hdet, nbg, ltn, lnl, pans, ws, B, K, NB);

    dim3 grid((N + 255) / 256, B);
    hipLaunchKernelGGL(pr_synth, grid, dim3(256), 0, stream,
                       ws, (float*)d_out, B, K, NB, N);
}

// Round 2
// 126.003 us; speedup vs baseline: 1.0104x; 1.0104x over previous
//
#include <hip/hip_runtime.h>
#include <math.h>

// ---------------------------------------------------------------------------
// PhysicsResonatorBank: B=8 notes, K=80 partials, NB=16 noise bands,
// N = n_frames*256 samples. out[b][c][n], c in {L,R}.
//
// Round-2 structure: one block = one n-tile (128 samples) x ALL notes.
// env/beat (b-independent) computed once per (k,n); per-(b,k) constants
// packed as float4 {2pi*f, ampL, ampR, 0} in LDS (broadcast reads).
// sin via 2-term f32 Cody-Waite reduction (q < 2^17 exact) + __sinf.
// ---------------------------------------------------------------------------

#define KMAX 128
#define NBMAX 32

#define C2PI_HI 6.28318548202514648f     // fl32(2*pi)
#define C2PI_LO -1.7484556e-7f           // fl32(2*pi - C2PI_HI)
#define INV2PI  0.15915494309189535f

__device__ __forceinline__ float nofuse(float x) {
    asm volatile("" : "+v"(x));
    return x;
}

__device__ __forceinline__ float sin_cw(float ph) {
    float q = rintf(ph * INV2PI);
    float r = fmaf(q, -C2PI_HI, ph);
    r = fmaf(q, -C2PI_LO, r);
    return __sinf(r);
}

// ws layout:
//  float4 pk4[B*K]  : {2pi*f, ampL, ampR, 0}
//  float4 keA[K]    : {1/tau1, 1/tau2, a1, 1-a1}
//  float4 keB[K]    : {2pi*beat_hz, 0.5*depth, 0, 0}
//  float4 nz [NB]   : {2pi*nf, band_gain, 0, 0}
//  float  nl [B]    : exp(log_noise_level)*vel
//  float  itn       : 1/tau_noise           (stored at nl[B])

__global__ void pr_precomp(const float* __restrict__ f0,
                           const float* __restrict__ vel,
                           const float* __restrict__ pslope,
                           const float* __restrict__ pinter,
                           const float* __restrict__ log_tau1,
                           const float* __restrict__ log_tau2,
                           const float* __restrict__ logit_a1,
                           const float* __restrict__ log_beat_hz,
                           const float* __restrict__ logit_beat_depth,
                           const float* __restrict__ log_A0,
                           const float* __restrict__ harm_detune,
                           const float* __restrict__ noise_band_gain,
                           const float* __restrict__ plog_tau_noise,
                           const float* __restrict__ plog_noise_level,
                           const float* __restrict__ ppan_scale,
                           float* __restrict__ ws, int B, int K, int NB) {
    const int tid = threadIdx.x;
    const float two_pi = C2PI_HI;
    const float slope = pslope[0], inter = pinter[0], pan_scale = ppan_scale[0];

    float4* pk4 = (float4*)ws;
    float4* keA = pk4 + (size_t)B * K;
    float4* keB = keA + K;
    float4* nz  = keB + K;
    float*  nl  = (float*)(nz + NB);

    for (int i = tid; i < B * K; i += blockDim.x) {
        int b = i / K, k = i % K;
        float f0b = f0[b];
        float kf = (float)(k + 1);
        // midi / inharmonicity (f64 transcendentals, f32 rounding chain)
        float fr = f0b / 440.0f;
        float midi = 69.0f + 12.0f * (float)log2((double)fr);
        float mn = (midi - 21.0f) / 87.0f;
        float z = nofuse(slope * mn) + inter;
        z = fminf(fmaxf(z, -14.0f), -4.0f);
        float Binh = (float)exp((double)z);
        // freq chain: replicate numpy's f32 rounding order exactly (no fma)
        float kk  = kf * kf;                       // exact
        float bk2 = nofuse(Binh * kk);
        float arg = nofuse(1.0f + bk2);
        float s3  = (float)sqrt((double)arg);      // correctly rounded
        float r0  = nofuse(f0b * kf);
        float r1  = nofuse(r0 * s3);
        float dt  = nofuse(1.0f + harm_detune[k]);
        float fq  = nofuse(r1 * dt);
        float alive = (fq < 22050.0f) ? 1.0f : 0.0f;
        float amp = (float)exp((double)log_A0[k]) * vel[b] * alive;
        // pan
        int km1 = (K - 1) > 1 ? (K - 1) : 1;
        float a = (float)k / (float)km1;
        float pini = nofuse((a * 2.0f - 1.0f) * 0.1f);
        float pexp = (float)exp((double)pan_scale);
        float pan = (float)tanh((double)nofuse(pini * pexp));
        float gl = (float)sqrt((double)(0.5f * (1.0f - pan)));
        float gr = (float)sqrt((double)(0.5f * (1.0f + pan)));
        float pf = nofuse(two_pi * fq);
        pk4[i] = make_float4(pf, amp * gl, amp * gr, 0.0f);
    }
    for (int k = tid; k < K; k += blockDim.x) {
        float tau1 = (float)exp((double)log_tau1[k]);
        float tau2 = (float)exp((double)log_tau2[k]);
        float a1 = (float)(1.0 / (1.0 + exp(-(double)logit_a1[k])));
        float bhz = (float)exp((double)log_beat_hz[k]);
        float dep = (float)(1.0 / (1.0 + exp(-(double)logit_beat_depth[k])));
        keA[k] = make_float4(1.0f / tau1, 1.0f / tau2, a1, 1.0f - a1);
        keB[k] = make_float4(nofuse(two_pi * bhz), 0.5f * dep, 0.0f, 0.0f);
    }
    for (int j = tid; j < NB; j += blockDim.x) {
        float m = -1e30f;
        for (int q = 0; q < NB; ++q) m = fmaxf(m, noise_band_gain[q]);
        float ssum = 0.0f;
        for (int q = 0; q < NB; ++q)
            ssum += (float)exp((double)(noise_band_gain[q] - m));
        double start = log(200.0), stop = log(20000.0);
        double step = (stop - start) / (double)(NB - 1);
        float lin = (j == NB - 1) ? (float)stop : (float)(start + (double)j * step);
        float nf = (float)exp((double)lin);
        float na = (nf < 22050.0f) ? 1.0f : 0.0f;
        float bg = ((float)exp((double)(noise_band_gain[j] - m)) / ssum) * na;
        nz[j] = make_float4(nofuse(two_pi * nf), bg, 0.0f, 0.0f);
    }
    for (int b = tid; b < B; b += blockDim.x)
        nl[b] = (float)exp((double)plog_noise_level[0]) * vel[b];
    if (tid == 0) nl[B] = 1.0f / (float)exp((double)plog_tau_noise[0]);
}

template <int BT>
__global__ __launch_bounds__(128) void pr_synth(
    const float4* __restrict__ pk4, const float4* __restrict__ keA,
    const float4* __restrict__ keB, const float4* __restrict__ nz,
    const float* __restrict__ nlp, float* __restrict__ out,
    int B, int K, int NB, int N) {
    __shared__ float4 s_pk[BT * KMAX];
    __shared__ float4 s_keA[KMAX];
    __shared__ float4 s_keB[KMAX];
    __shared__ float4 s_nz[NBMAX];
    __shared__ float  s_nl[BT];
    __shared__ float  s_itn;

    const int tid = threadIdx.x;
    const int bOff = blockIdx.y * BT;

    for (int i = tid; i < BT * K; i += blockDim.x) {
        int bi = i / K, k = i - bi * K;
        int b = bOff + bi;
        s_pk[i] = (b < B) ? pk4[(size_t)b * K + k] : make_float4(0, 0, 0, 0);
    }
    for (int i = tid; i < K; i += blockDim.x) {
        s_keA[i] = keA[i];
        s_keB[i] = keB[i];
    }
    for (int i = tid; i < NB; i += blockDim.x) s_nz[i] = nz[i];
    for (int i = tid; i < BT; i += blockDim.x)
        s_nl[i] = (bOff + i < B) ? nlp[bOff + i] : 0.0f;
    if (tid == 0) s_itn = nlp[B];
    __syncthreads();

    const int n = blockIdx.x * blockDim.x + tid;
    if (n >= N) return;
    const float t = (float)n * (float)(1.0 / 44100.0);
    const float nt = -t;

    float accL[BT], accR[BT];
#pragma unroll
    for (int bi = 0; bi < BT; ++bi) { accL[bi] = 0.0f; accR[bi] = 0.0f; }

    for (int k = 0; k < K; ++k) {
        float4 ka = s_keA[k];
        float4 kb = s_keB[k];
        float e1 = __expf(nt * ka.x);
        float e2 = __expf(nt * ka.y);
        float env = ka.z * e1 + ka.w * e2;
        float beat = fmaf(kb.y, __cosf(kb.x * t) - 1.0f, 1.0f);
        float eb = env * beat;
#pragma unroll
        for (int bi = 0; bi < BT; ++bi) {
            float4 p = s_pk[bi * K + k];
            float ph = p.x * t;
            float q = rintf(ph * INV2PI);
            float r = fmaf(q, -C2PI_HI, ph);
            r = fmaf(q, -C2PI_LO, r);
            float sv = __sinf(r);
            float pp = eb * sv;
            accL[bi] = fmaf(p.y, pp, accL[bi]);
            accR[bi] = fmaf(p.z, pp, accR[bi]);
        }
    }

    float ns = 0.0f;
    for (int j = 0; j < NB; ++j) {
        float4 zj = s_nz[j];
        ns = fmaf(zj.y, sin_cw(zj.x * t), ns);
    }
    float nsv = ns * __expf(nt * s_itn);

#pragma unroll
    for (int bi = 0; bi < BT; ++bi) {
        int b = bOff + bi;
        if (b < B) {
            float nois = s_nl[bi] * nsv;
            out[((size_t)(b * 2 + 0)) * N + n] = accL[bi] + nois;
            out[((size_t)(b * 2 + 1)) * N + n] = accR[bi] + nois;
        }
    }
}

extern "C" void kernel_launch(void* const* d_in, const int* in_sizes, int n_in,
                              void* d_out, int out_size, void* d_ws, size_t ws_size,
                              hipStream_t stream) {
    const float* f0    = (const float*)d_in[0];
    const float* vel   = (const float*)d_in[1];
    const float* slope = (const float*)d_in[2];
    const float* inter = (const float*)d_in[3];
    const float* lt1   = (const float*)d_in[4];
    const float* lt2   = (const float*)d_in[5];
    const float* la1   = (const float*)d_in[6];
    const float* lbh   = (const float*)d_in[7];
    const float* lbd   = (const float*)d_in[8];
    const float* lA0   = (const float*)d_in[9];
    const float* hdet  = (const float*)d_in[10];
    const float* nbg   = (const float*)d_in[11];
    const float* ltn   = (const float*)d_in[12];
    const float* lnl   = (const float*)d_in[13];
    const float* pans  = (const float*)d_in[14];

    const int B  = in_sizes[0];
    const int K  = in_sizes[4];
    const int NB = in_sizes[11];
    const int N  = out_size / (2 * B);

    float* ws = (float*)d_ws;

    hipLaunchKernelGGL(pr_precomp, dim3(1), dim3(256), 0, stream,
                       f0, vel, slope, inter, lt1, lt2, la1, lbh, lbd, lA0,
                       hdet, nbg, ltn, lnl, pans, ws, B, K, NB);

    const float4* pk4 = (const float4*)ws;
    const float4* keA = pk4 + (size_t)B * K;
    const float4* keB = keA + K;
    const float4* nz  = keB + K;
    const float*  nlp = (const float*)(nz + NB);

    dim3 grid((N + 127) / 128, (B + 7) / 8);
    hipLaunchKernelGGL(pr_synth<8>, grid, dim3(128), 0, stream,
                       pk4, keA, keB, nz, nlp, (float*)d_out, B, K, NB, N);
}

// Round 4
// 120.836 us; speedup vs baseline: 1.0537x; 1.0428x over previous
//
#include <hip/hip_runtime.h>
#include <math.h>

// ---------------------------------------------------------------------------
// PhysicsResonatorBank: B=8 notes, K=80 partials, NB=16 noise bands,
// N = n_frames*256 samples. out[b][c][n], c in {L,R}.
//
// Round-3 structure: K split into NCH=4 chunks across blockIdx.y so the
// grid has 4x the waves (4/SIMD, ~50% occupancy) while env/beat is still
// computed exactly once per (k,n). Stage A writes per-chunk partial sums
// (16.8 MB) to ws; stage B sums 4 partials + attack noise -> out.
// sin via 2-term f32 Cody-Waite reduction of the reference's exact f32
// phase fl(fl(2pi*f)*t), then hw __sinf on the small residual.
// ---------------------------------------------------------------------------

#define KMAX 128
#define NBMAX 32
#define NCH 4
#define KCMAX 32

#define C2PI_HI 6.28318548202514648f     // fl32(2*pi)
#define C2PI_LO -1.7484556e-7f           // fl32(2*pi - C2PI_HI)
#define INV2PI  0.15915494309189535f

__device__ __forceinline__ float nofuse(float x) {
    asm volatile("" : "+v"(x));
    return x;
}

__device__ __forceinline__ float sin_cw(float ph) {
    float q = rintf(ph * INV2PI);
    float r = fmaf(q, -C2PI_HI, ph);
    r = fmaf(q, -C2PI_LO, r);
    return __sinf(r);
}

// ws layout (floats):
//  float4 pk4[B*K]  : {2pi*f, ampL, ampR, 0}
//  float4 keA[K]    : {1/tau1, 1/tau2, a1, 1-a1}
//  float4 keB[K]    : {2pi*beat_hz, 0.5*depth, 0, 0}
//  float4 nz [NB]   : {2pi*nf, band_gain, 0, 0}
//  float  nl [B]    : exp(log_noise_level)*vel ; nl[B] = 1/tau_noise
//  ... at float offset PART_OFF: part[(c*2B + j)*N + n], j = b*2+ch
#define PART_OFF 16384

__global__ void pr_precomp(const float* __restrict__ f0,
                           const float* __restrict__ vel,
                           const float* __restrict__ pslope,
                           const float* __restrict__ pinter,
                           const float* __restrict__ log_tau1,
                           const float* __restrict__ log_tau2,
                           const float* __restrict__ logit_a1,
                           const float* __restrict__ log_beat_hz,
                           const float* __restrict__ logit_beat_depth,
                           const float* __restrict__ log_A0,
                           const float* __restrict__ harm_detune,
                           const float* __restrict__ noise_band_gain,
                           const float* __restrict__ plog_tau_noise,
                           const float* __restrict__ plog_noise_level,
                           const float* __restrict__ ppan_scale,
                           float* __restrict__ ws, int B, int K, int NB) {
    const int tid = threadIdx.x;
    const float two_pi = C2PI_HI;
    const float slope = pslope[0], inter = pinter[0], pan_scale = ppan_scale[0];

    float4* pk4 = (float4*)ws;
    float4* keA = pk4 + (size_t)B * K;
    float4* keB = keA + K;
    float4* nz  = keB + K;
    float*  nl  = (float*)(nz + NB);

    for (int i = tid; i < B * K; i += blockDim.x) {
        int b = i / K, k = i % K;
        float f0b = f0[b];
        float kf = (float)(k + 1);
        float fr = f0b / 440.0f;
        float midi = 69.0f + 12.0f * (float)log2((double)fr);
        float mn = (midi - 21.0f) / 87.0f;
        float z = nofuse(slope * mn) + inter;
        z = fminf(fmaxf(z, -14.0f), -4.0f);
        float Binh = (float)exp((double)z);
        float kk  = kf * kf;
        float bk2 = nofuse(Binh * kk);
        float arg = nofuse(1.0f + bk2);
        float s3  = (float)sqrt((double)arg);
        float r0  = nofuse(f0b * kf);
        float r1  = nofuse(r0 * s3);
        float dt  = nofuse(1.0f + harm_detune[k]);
        float fq  = nofuse(r1 * dt);
        float alive = (fq < 22050.0f) ? 1.0f : 0.0f;
        float amp = (float)exp((double)log_A0[k]) * vel[b] * alive;
        int km1 = (K - 1) > 1 ? (K - 1) : 1;
        float a = (float)k / (float)km1;
        float pini = nofuse((a * 2.0f - 1.0f) * 0.1f);
        float pexp = (float)exp((double)pan_scale);
        float pan = (float)tanh((double)nofuse(pini * pexp));
        float gl = (float)sqrt((double)(0.5f * (1.0f - pan)));
        float gr = (float)sqrt((double)(0.5f * (1.0f + pan)));
        float pf = nofuse(two_pi * fq);
        pk4[i] = make_float4(pf, amp * gl, amp * gr, 0.0f);
    }
    for (int k = tid; k < K; k += blockDim.x) {
        float tau1 = (float)exp((double)log_tau1[k]);
        float tau2 = (float)exp((double)log_tau2[k]);
        float a1 = (float)(1.0 / (1.0 + exp(-(double)logit_a1[k])));
        float bhz = (float)exp((double)log_beat_hz[k]);
        float dep = (float)(1.0 / (1.0 + exp(-(double)logit_beat_depth[k])));
        keA[k] = make_float4(1.0f / tau1, 1.0f / tau2, a1, 1.0f - a1);
        keB[k] = make_float4(nofuse(two_pi * bhz), 0.5f * dep, 0.0f, 0.0f);
    }
    for (int j = tid; j < NB; j += blockDim.x) {
        float m = -1e30f;
        for (int q = 0; q < NB; ++q) m = fmaxf(m, noise_band_gain[q]);
        float ssum = 0.0f;
        for (int q = 0; q < NB; ++q)
            ssum += (float)exp((double)(noise_band_gain[q] - m));
        double start = log(200.0), stop = log(20000.0);
        double step = (stop - start) / (double)(NB - 1);
        float lin = (j == NB - 1) ? (float)stop : (float)(start + (double)j * step);
        float nf = (float)exp((double)lin);
        float na = (nf < 22050.0f) ? 1.0f : 0.0f;
        float bg = ((float)exp((double)(noise_band_gain[j] - m)) / ssum) * na;
        nz[j] = make_float4(nofuse(two_pi * nf), bg, 0.0f, 0.0f);
    }
    for (int b = tid; b < B; b += blockDim.x)
        nl[b] = (float)exp((double)plog_noise_level[0]) * vel[b];
    if (tid == 0) nl[B] = 1.0f / (float)exp((double)plog_tau_noise[0]);
}

// Stage A: per-chunk partial oscillator-bank sums for all B notes.
template <int BT>
__global__ __launch_bounds__(256) void pr_part(
    const float4* __restrict__ pk4, const float4* __restrict__ keA,
    const float4* __restrict__ keB, float* __restrict__ part,
    int B, int K, int N) {
    const int KC = (K + NCH - 1) / NCH;
    const int c = blockIdx.y;
    const int k0 = c * KC;
    const int k1 = min(K, k0 + KC);
    const int nk = k1 - k0;

    __shared__ float4 s_pk[BT * KCMAX];
    __shared__ float4 s_keA[KCMAX];
    __shared__ float4 s_keB[KCMAX];

    const int tid = threadIdx.x;
    for (int i = tid; i < BT * nk; i += blockDim.x) {
        int bi = i / nk, kk = i - bi * nk;
        s_pk[bi * KCMAX + kk] = pk4[(size_t)bi * K + k0 + kk];
    }
    for (int i = tid; i < nk; i += blockDim.x) {
        s_keA[i] = keA[k0 + i];
        s_keB[i] = keB[k0 + i];
    }
    __syncthreads();

    const int n = blockIdx.x * blockDim.x + tid;
    if (n >= N) return;
    const float t = (float)n * (float)(1.0 / 44100.0);
    const float nt = -t;

    float accL[BT], accR[BT];
#pragma unroll
    for (int bi = 0; bi < BT; ++bi) { accL[bi] = 0.0f; accR[bi] = 0.0f; }

    for (int kk = 0; kk < nk; ++kk) {
        float4 ka = s_keA[kk];
        float4 kb = s_keB[kk];
        float e1 = __expf(nt * ka.x);
        float e2 = __expf(nt * ka.y);
        float env = ka.z * e1 + ka.w * e2;
        float beat = fmaf(kb.y, __cosf(kb.x * t) - 1.0f, 1.0f);
        float eb = env * beat;
#pragma unroll
        for (int bi = 0; bi < BT; ++bi) {
            float4 p = s_pk[bi * KCMAX + kk];
            float ph = p.x * t;
            float q = rintf(ph * INV2PI);
            float r = fmaf(q, -C2PI_HI, ph);
            r = fmaf(q, -C2PI_LO, r);
            float sv = __sinf(r);
            float pp = eb * sv;
            accL[bi] = fmaf(p.y, pp, accL[bi]);
            accR[bi] = fmaf(p.z, pp, accR[bi]);
        }
    }

#pragma unroll
    for (int bi = 0; bi < BT; ++bi) {
        part[((size_t)(c * 2 * BT + bi * 2 + 0)) * N + n] = accL[bi];
        part[((size_t)(c * 2 * BT + bi * 2 + 1)) * N + n] = accR[bi];
    }
}

// Stage B: sum chunk partials + attack noise -> out.
template <int BT>
__global__ __launch_bounds__(256) void pr_comb(
    const float* __restrict__ part, const float4* __restrict__ nz,
    const float* __restrict__ nlp, float* __restrict__ out,
    int B, int NB, int N) {
    __shared__ float4 s_nz[NBMAX];
    __shared__ float  s_nl[BT + 1];
    const int tid = threadIdx.x;
    for (int i = tid; i < NB; i += blockDim.x) s_nz[i] = nz[i];
    for (int i = tid; i < BT + 1; i += blockDim.x) s_nl[i] = nlp[i];
    __syncthreads();

    const int n = blockIdx.x * blockDim.x + tid;
    if (n >= N) return;
    const float t = (float)n * (float)(1.0 / 44100.0);

    float ns = 0.0f;
    for (int j = 0; j < NB; ++j) {
        float4 zj = s_nz[j];
        ns = fmaf(zj.y, sin_cw(zj.x * t), ns);
    }
    float nsv = ns * __expf(-t * s_nl[BT]);

#pragma unroll
    for (int j = 0; j < 2 * BT; ++j) {
        float s = part[(size_t)j * N + n];
#pragma unroll
        for (int c = 1; c < NCH; ++c)
            s += part[((size_t)(c * 2 * BT + j)) * N + n];
        float nois = s_nl[j >> 1] * nsv;
        out[(size_t)j * N + n] = s + nois;
    }
}

extern "C" void kernel_launch(void* const* d_in, const int* in_sizes, int n_in,
                              void* d_out, int out_size, void* d_ws, size_t ws_size,
                              hipStream_t stream) {
    const float* f0    = (const float*)d_in[0];
    const float* vel   = (const float*)d_in[1];
    const float* slope = (const float*)d_in[2];
    const float* inter = (const float*)d_in[3];
    const float* lt1   = (const float*)d_in[4];
    const float* lt2   = (const float*)d_in[5];
    const float* la1   = (const float*)d_in[6];
    const float* lbh   = (const float*)d_in[7];
    const float* lbd   = (const float*)d_in[8];
    const float* lA0   = (const float*)d_in[9];
    const float* hdet  = (const float*)d_in[10];
    const float* nbg   = (const float*)d_in[11];
    const float* ltn   = (const float*)d_in[12];
    const float* lnl   = (const float*)d_in[13];
    const float* pans  = (const float*)d_in[14];

    const int B  = in_sizes[0];
    const int K  = in_sizes[4];
    const int NB = in_sizes[11];
    const int N  = out_size / (2 * B);

    float* ws = (float*)d_ws;

    hipLaunchKernelGGL(pr_precomp, dim3(1), dim3(256), 0, stream,
                       f0, vel, slope, inter, lt1, lt2, la1, lbh, lbd, lA0,
                       hdet, nbg, ltn, lnl, pans, ws, B, K, NB);

    const float4* pk4 = (const float4*)ws;
    const float4* keA = pk4 + (size_t)B * K;
    const float4* keB = keA + K;
    const float4* nz  = keB + K;
    const float*  nlp = (const float*)(nz + NB);
    float* part = ws + PART_OFF;

    dim3 gridA((N + 255) / 256, NCH);
    hipLaunchKernelGGL(pr_part<8>, gridA, dim3(256), 0, stream,
                       pk4, keA, keB, part, B, K, N);

    dim3 gridB((N + 255) / 256);
    hipLaunchKernelGGL(pr_comb<8>, gridB, dim3(256), 0, stream,
                       part, nz, nlp, (float*)d_out, B, NB, N);
}

// Round 5
// 110.170 us; speedup vs baseline: 1.1557x; 1.0968x over previous
//
#include <hip/hip_runtime.h>
#include <math.h>

// ---------------------------------------------------------------------------
// PhysicsResonatorBank: B=8 notes, K=80 partials, NB=16 noise bands,
// N = n_frames*256 samples. out[b][c][n], c in {L,R}.
//
// Round-5 structure: SINGLE fused synth kernel. Block = 256 threads =
// 4 waves; wave g computes k-chunk g (K/4 partials) for 64 samples x all
// B notes (env/beat once per (k,n) since each k lives in one chunk).
// Chunk partials exchanged via padded LDS [NCH][64][17] (conflict-free),
// epilogue (chunk-sum + attack noise + store) split 4-ways across waves.
// sin via 2-term f32 Cody-Waite reduction of the reference's exact f32
// phase fl(fl(2pi*f)*t), then hw __sinf on the small residual.
// ---------------------------------------------------------------------------

#define KMAX 128
#define NBMAX 32
#define NCH 4

#define C2PI_HI 6.28318548202514648f     // fl32(2*pi)
#define C2PI_LO -1.7484556e-7f           // fl32(2*pi - C2PI_HI)
#define INV2PI  0.15915494309189535f

__device__ __forceinline__ float nofuse(float x) {
    asm volatile("" : "+v"(x));
    return x;
}

__device__ __forceinline__ float sin_cw(float ph) {
    float q = rintf(ph * INV2PI);
    float r = fmaf(q, -C2PI_HI, ph);
    r = fmaf(q, -C2PI_LO, r);
    return __sinf(r);
}

// ws layout (floats):
//  float4 pk4[B*K]  : {2pi*f, ampL, ampR, 0}
//  float4 keA[K]    : {1/tau1, 1/tau2, a1, 1-a1}
//  float4 keB[K]    : {2pi*beat_hz, 0.5*depth, 0, 0}
//  float4 nz [NB]   : {2pi*nf, band_gain, 0, 0}
//  float  nl [B]    : exp(log_noise_level)*vel ; nl[B] = 1/tau_noise

__global__ void pr_precomp(const float* __restrict__ f0,
                           const float* __restrict__ vel,
                           const float* __restrict__ pslope,
                           const float* __restrict__ pinter,
                           const float* __restrict__ log_tau1,
                           const float* __restrict__ log_tau2,
                           const float* __restrict__ logit_a1,
                           const float* __restrict__ log_beat_hz,
                           const float* __restrict__ logit_beat_depth,
                           const float* __restrict__ log_A0,
                           const float* __restrict__ harm_detune,
                           const float* __restrict__ noise_band_gain,
                           const float* __restrict__ plog_tau_noise,
                           const float* __restrict__ plog_noise_level,
                           const float* __restrict__ ppan_scale,
                           float* __restrict__ ws, int B, int K, int NB) {
    const int tid = threadIdx.x;
    const int b = blockIdx.x;           // grid = B blocks
    const float two_pi = C2PI_HI;
    const float slope = pslope[0], inter = pinter[0], pan_scale = ppan_scale[0];

    float4* pk4 = (float4*)ws;
    float4* keA = pk4 + (size_t)B * K;
    float4* keB = keA + K;
    float4* nz  = keB + K;
    float*  nl  = (float*)(nz + NB);

    // per-(b,k) oscillator constants: this block handles note b
    {
        float f0b = f0[b];
        float fr = f0b / 440.0f;
        float midi = 69.0f + 12.0f * (float)log2((double)fr);
        float mn = (midi - 21.0f) / 87.0f;
        float z = nofuse(slope * mn) + inter;
        z = fminf(fmaxf(z, -14.0f), -4.0f);
        float Binh = (float)exp((double)z);
        float pexp = (float)exp((double)pan_scale);
        int km1 = (K - 1) > 1 ? (K - 1) : 1;
        for (int k = tid; k < K; k += blockDim.x) {
            float kf = (float)(k + 1);
            float kk  = kf * kf;
            float bk2 = nofuse(Binh * kk);
            float arg = nofuse(1.0f + bk2);
            float s3  = (float)sqrt((double)arg);
            float r0  = nofuse(f0b * kf);
            float r1  = nofuse(r0 * s3);
            float dt  = nofuse(1.0f + harm_detune[k]);
            float fq  = nofuse(r1 * dt);
            float alive = (fq < 22050.0f) ? 1.0f : 0.0f;
            float amp = (float)exp((double)log_A0[k]) * vel[b] * alive;
            float a = (float)k / (float)km1;
            float pini = nofuse((a * 2.0f - 1.0f) * 0.1f);
            float pan = (float)tanh((double)nofuse(pini * pexp));
            float gl = (float)sqrt((double)(0.5f * (1.0f - pan)));
            float gr = (float)sqrt((double)(0.5f * (1.0f + pan)));
            float pf = nofuse(two_pi * fq);
            pk4[(size_t)b * K + k] = make_float4(pf, amp * gl, amp * gr, 0.0f);
        }
    }

    if (b != 0) return;
    // shared (b-independent) tables: block 0 only
    for (int k = tid; k < K; k += blockDim.x) {
        float tau1 = (float)exp((double)log_tau1[k]);
        float tau2 = (float)exp((double)log_tau2[k]);
        float a1 = (float)(1.0 / (1.0 + exp(-(double)logit_a1[k])));
        float bhz = (float)exp((double)log_beat_hz[k]);
        float dep = (float)(1.0 / (1.0 + exp(-(double)logit_beat_depth[k])));
        keA[k] = make_float4(1.0f / tau1, 1.0f / tau2, a1, 1.0f - a1);
        keB[k] = make_float4(nofuse(two_pi * bhz), 0.5f * dep, 0.0f, 0.0f);
    }
    for (int j = tid; j < NB; j += blockDim.x) {
        float m = -1e30f;
        for (int q = 0; q < NB; ++q) m = fmaxf(m, noise_band_gain[q]);
        float ssum = 0.0f;
        for (int q = 0; q < NB; ++q)
            ssum += (float)exp((double)(noise_band_gain[q] - m));
        double start = log(200.0), stop = log(20000.0);
        double step = (stop - start) / (double)(NB - 1);
        float lin = (j == NB - 1) ? (float)stop : (float)(start + (double)j * step);
        float nf = (float)exp((double)lin);
        float na = (nf < 22050.0f) ? 1.0f : 0.0f;
        float bg = ((float)exp((double)(noise_band_gain[j] - m)) / ssum) * na;
        nz[j] = make_float4(nofuse(two_pi * nf), bg, 0.0f, 0.0f);
    }
    for (int bb = tid; bb < B; bb += blockDim.x)
        nl[bb] = (float)exp((double)plog_noise_level[0]) * vel[bb];
    if (tid == 0) nl[B] = 1.0f / (float)exp((double)plog_tau_noise[0]);
}

// Fused synth: block = 64 samples x all notes; 4 waves = 4 K-chunks;
// LDS exchange + 4-way-split epilogue.
template <int BT>
__global__ __launch_bounds__(256, 4) void pr_synth(
    const float4* __restrict__ pk4, const float4* __restrict__ keA,
    const float4* __restrict__ keB, const float4* __restrict__ nz,
    const float* __restrict__ nlp, float* __restrict__ out,
    int B, int K, int NB, int N) {
    __shared__ float4 s_pk[BT * KMAX];
    __shared__ float4 s_keA[KMAX];
    __shared__ float4 s_keB[KMAX];
    __shared__ float4 s_nz[NBMAX];
    __shared__ float  s_red[NCH][64][2 * BT + 1];   // stride 17: conflict-free

    const int tid  = threadIdx.x;
    const int lane = tid & 63;
    const int g    = tid >> 6;          // wave index = k-chunk

    for (int i = tid; i < BT * K; i += blockDim.x) {
        int bi = i / K, k = i - bi * K;
        s_pk[bi * KMAX + k] =
            (bi < B) ? pk4[(size_t)bi * K + k] : make_float4(0, 0, 0, 0);
    }
    for (int i = tid; i < K; i += blockDim.x) {
        s_keA[i] = keA[i];
        s_keB[i] = keB[i];
    }
    for (int i = tid; i < NB; i += blockDim.x) s_nz[i] = nz[i];
    __syncthreads();

    const int n = blockIdx.x * 64 + lane;
    const float t = (float)n * (float)(1.0 / 44100.0);
    const float nt = -t;
    const int KC = (K + NCH - 1) / NCH;
    const int k0 = g * KC;
    const int k1 = min(K, k0 + KC);

    float accL[BT], accR[BT];
#pragma unroll
    for (int bi = 0; bi < BT; ++bi) { accL[bi] = 0.0f; accR[bi] = 0.0f; }

    for (int k = k0; k < k1; ++k) {
        float4 ka = s_keA[k];
        float4 kb = s_keB[k];
        float e1 = __expf(nt * ka.x);
        float e2 = __expf(nt * ka.y);
        float env = ka.z * e1 + ka.w * e2;
        float beat = fmaf(kb.y, __cosf(kb.x * t) - 1.0f, 1.0f);
        float eb = env * beat;
#pragma unroll
        for (int bi = 0; bi < BT; ++bi) {
            float4 p = s_pk[bi * KMAX + k];
            float ph = p.x * t;
            float q = rintf(ph * INV2PI);
            float r = fmaf(q, -C2PI_HI, ph);
            r = fmaf(q, -C2PI_LO, r);
            float sv = __sinf(r);
            float pp = eb * sv;
            accL[bi] = fmaf(p.y, pp, accL[bi]);
            accR[bi] = fmaf(p.z, pp, accR[bi]);
        }
    }

#pragma unroll
    for (int bi = 0; bi < BT; ++bi) {
        s_red[g][lane][2 * bi + 0] = accL[bi];
        s_red[g][lane][2 * bi + 1] = accR[bi];
    }
    __syncthreads();

    // attack noise (computed per wave; 16 sins, redundant x4 waves)
    float ns = 0.0f;
    for (int j = 0; j < NB; ++j) {
        float4 zj = s_nz[j];
        ns = fmaf(zj.y, sin_cw(zj.x * t), ns);
    }
    float nsv = ns * __expf(nt * nlp[B]);

    const int JT = (2 * BT) / NCH;      // outputs per wave (4)
    if (n < N) {
#pragma unroll
        for (int jj = 0; jj < JT; ++jj) {
            int j = g * JT + jj;
            int b = j >> 1;
            if (b >= B) continue;
            float s = 0.0f;
#pragma unroll
            for (int c = 0; c < NCH; ++c) s += s_red[c][lane][j];
            float nois = nlp[b] * nsv;
            out[(size_t)j * N + n] = s + nois;
        }
    }
}

extern "C" void kernel_launch(void* const* d_in, const int* in_sizes, int n_in,
                              void* d_out, int out_size, void* d_ws, size_t ws_size,
                              hipStream_t stream) {
    const float* f0    = (const float*)d_in[0];
    const float* vel   = (const float*)d_in[1];
    const float* slope = (const float*)d_in[2];
    const float* inter = (const float*)d_in[3];
    const float* lt1   = (const float*)d_in[4];
    const float* lt2   = (const float*)d_in[5];
    const float* la1   = (const float*)d_in[6];
    const float* lbh   = (const float*)d_in[7];
    const float* lbd   = (const float*)d_in[8];
    const float* lA0   = (const float*)d_in[9];
    const float* hdet  = (const float*)d_in[10];
    const float* nbg   = (const float*)d_in[11];
    const float* ltn   = (const float*)d_in[12];
    const float* lnl   = (const float*)d_in[13];
    const float* pans  = (const float*)d_in[14];

    const int B  = in_sizes[0];
    const int K  = in_sizes[4];
    const int NB = in_sizes[11];
    const int N  = out_size / (2 * B);

    float* ws = (float*)d_ws;

    hipLaunchKernelGGL(pr_precomp, dim3(B), dim3(128), 0, stream,
                       f0, vel, slope, inter, lt1, lt2, la1, lbh, lbd, lA0,
                       hdet, nbg, ltn, lnl, pans, ws, B, K, NB);

    const float4* pk4 = (const float4*)ws;
    const float4* keA = pk4 + (size_t)B * K;
    const float4* keB = keA + K;
    const float4* nz  = keB + K;
    const float*  nlp = (const float*)(nz + NB);

    dim3 grid((N + 63) / 64);
    hipLaunchKernelGGL(pr_synth<8>, grid, dim3(256), 0, stream,
                       pk4, keA, keB, nz, nlp, (float*)d_out, B, K, NB, N);
}